// Round 10
// baseline (391.481 us; speedup 1.0000x reference)
//
#include <hip/hip_runtime.h>
#include <hip/hip_bf16.h>
#include <math.h>

// Problem constants
#define B_  128
#define L_  256
#define E_  300
#define PF_ 50
#define D_  400      // E + 2*PF
#define D3_ 1200     // 3*D
#define C_  512
#define KW_ 3
#define R_  53
#define M_  (B_*L_)  // 32768
#define KP_ 1216     // padded per-tap K (1200 -> 1216, divisible by 64)
#define K3_ (3*KP_)  // 3648 total GEMM K
#define LROWS_ 258   // L + 2 padded rows per batch in XSp

typedef __attribute__((ext_vector_type(8))) short bf16x8;
typedef __attribute__((ext_vector_type(8))) unsigned short u16x8;
typedef __attribute__((ext_vector_type(4))) float f32x4;

__device__ __forceinline__ unsigned short f2bf(float f) {
    union { float f; unsigned u; } x; x.f = f;
    unsigned r = x.u + 0x7FFF + ((x.u >> 16) & 1);
    return (unsigned short)(r >> 16);
}
__device__ __forceinline__ float bf2f(unsigned short u) {
    union { unsigned u; float f; } x; x.u = ((unsigned)u) << 16;
    return x.f;
}

__device__ __forceinline__ void gld16(const void* g, void* l) {
    __builtin_amdgcn_global_load_lds(
        (const __attribute__((address_space(1))) void*)g,
        (__attribute__((address_space(3))) void*)l, 16, 0, 0);
}

// ---------------- prep: WpT[c][q] = conv_w[c, ch, k], q = k*1216+ch, zero-pad ch>=1200
__global__ void prep_wpT_kernel(const float* __restrict__ conv_w, unsigned short* __restrict__ WpT) {
    int idx = blockIdx.x * blockDim.x + threadIdx.x;
    if (idx >= C_ * K3_) return;
    int c = idx / K3_, q = idx % K3_;
    int k = q / KP_, ch = q % KP_;
    WpT[idx] = (ch < D3_) ? f2bf(conv_w[c * (D3_ * KW_) + ch * KW_ + k]) : (unsigned short)0;
}

// ---------------- prep: MmatT[n][k] = sum_r rlw[r,k]*re[r,n]  (bf16)
__global__ void prep_mT_kernel(const float* __restrict__ rlw, const float* __restrict__ re,
                               unsigned short* __restrict__ MmatT) {
    int idx = blockIdx.x * blockDim.x + threadIdx.x;
    if (idx >= C_ * C_) return;
    int n = idx / C_, k = idx % C_;
    float acc = 0.f;
    for (int r = 0; r < R_; ++r)
        acc += rlw[r * C_ + k] * re[r * C_ + n];
    MmatT[idx] = f2bf(acc);
}

// ---------------- wf[b,t,d] f32
__global__ void build_wf_kernel(const int* __restrict__ ctx, const int* __restrict__ sdis,
                                const int* __restrict__ odis, const float* __restrict__ emb,
                                const float* __restrict__ pos, float* __restrict__ wf) {
    const int total = M_ * D_;
    for (int idx = blockIdx.x * blockDim.x + threadIdx.x; idx < total;
         idx += gridDim.x * blockDim.x) {
        int d = idx % D_;
        int bt = idx / D_;
        float v;
        if (d < E_)            v = emb[(long)ctx[bt] * E_ + d];
        else if (d < E_ + PF_) v = pos[sdis[bt] * PF_ + (d - E_)];
        else                   v = pos[odis[bt] * PF_ + (d - E_ - PF_)];
        wf[idx] = v;
    }
}

// ---------------- FUSED attention-scale: span sums + dots + softmax -> s[b,t]
// One block per batch. Phase 1: thread d streams wf[b][*][d] once, accumulating the
// 6 span sums in registers (row u contributes to span j iff u+1-j in [lo,hi]).
// Phase 2: wave per t, dots vs LDS span means (wf[b] is L2-hot). Phase 3: softmax.
__global__ __launch_bounds__(512) void attn_fused_kernel(
    const float* __restrict__ wf, const int* __restrict__ sidx, const int* __restrict__ oidx,
    float* __restrict__ s) {
    const int b = blockIdx.x;
    const int tid = threadIdx.x;
    __shared__ float subjS[3][D_];
    __shared__ float objS[3][D_];
    __shared__ float dbuf[2][L_];
    __shared__ float red[512];

    const int s0 = sidx[b * 2], s1 = sidx[b * 2 + 1];
    const int o0 = oidx[b * 2], o1 = oidx[b * 2 + 1];
    const float sinv = 1.0f / (float)(s1 - s0 + 1);
    const float oinv = 1.0f / (float)(o1 - o0 + 1);

    if (tid < D_) {
        float ss0 = 0.f, ss1 = 0.f, ss2 = 0.f, oo0 = 0.f, oo1 = 0.f, oo2 = 0.f;
        const float* col = wf + (size_t)(b << 8) * D_ + tid;
        for (int t = 0; t < L_; ++t) {
            float v = col[(size_t)t * D_];
            int t1 = t + 1;
            if (t1 - 0 >= s0 && t1 - 0 <= s1) ss0 += v;
            if (t1 - 1 >= s0 && t1 - 1 <= s1) ss1 += v;
            if (t1 - 2 >= s0 && t1 - 2 <= s1) ss2 += v;
            if (t1 - 0 >= o0 && t1 - 0 <= o1) oo0 += v;
            if (t1 - 1 >= o0 && t1 - 1 <= o1) oo1 += v;
            if (t1 - 2 >= o0 && t1 - 2 <= o1) oo2 += v;
        }
        subjS[0][tid] = ss0 * sinv; subjS[1][tid] = ss1 * sinv; subjS[2][tid] = ss2 * sinv;
        objS[0][tid] = oo0 * oinv;  objS[1][tid] = oo1 * oinv;  objS[2][tid] = oo2 * oinv;
    }
    __syncthreads();

    const int wv = tid >> 6, lane = tid & 63;
    for (int t = wv; t < L_; t += 8) {
        float ds = 0.f, dd = 0.f;
#pragma unroll
        for (int j = 0; j < 3; ++j) {
            int u = t + j - 1;
            if ((unsigned)u < (unsigned)L_) {
                const float4* w4 = (const float4*)(wf + ((size_t)((b << 8) + u)) * D_);
                const float4* s4 = (const float4*)&subjS[j][0];
                const float4* o4 = (const float4*)&objS[j][0];
                for (int q = lane; q < D_ / 4; q += 64) {
                    float4 wv4 = w4[q], sv = s4[q], ov = o4[q];
                    ds += wv4.x * sv.x + wv4.y * sv.y + wv4.z * sv.z + wv4.w * sv.w;
                    dd += wv4.x * ov.x + wv4.y * ov.y + wv4.z * ov.z + wv4.w * ov.w;
                }
            }
        }
#pragma unroll
        for (int off = 32; off > 0; off >>= 1) {
            ds += __shfl_down(ds, off);
            dd += __shfl_down(dd, off);
        }
        if (lane == 0) { dbuf[0][t] = ds; dbuf[1][t] = dd; }
    }
    __syncthreads();

    float ds = (tid < L_) ? dbuf[0][tid] : -INFINITY;
    float dd = (tid < L_) ? dbuf[1][tid] : -INFINITY;

    red[tid] = ds; __syncthreads();
    for (int st = 256; st > 0; st >>= 1) {
        if (tid < st) red[tid] = fmaxf(red[tid], red[tid + st]);
        __syncthreads();
    }
    float ms = red[0]; __syncthreads();
    float es = (tid < L_) ? expf(ds - ms) : 0.f;
    red[tid] = es; __syncthreads();
    for (int st = 256; st > 0; st >>= 1) {
        if (tid < st) red[tid] += red[tid + st];
        __syncthreads();
    }
    float zs = red[0]; __syncthreads();

    red[tid] = dd; __syncthreads();
    for (int st = 256; st > 0; st >>= 1) {
        if (tid < st) red[tid] = fmaxf(red[tid], red[tid + st]);
        __syncthreads();
    }
    float mo = red[0]; __syncthreads();
    float eo = (tid < L_) ? expf(dd - mo) : 0.f;
    red[tid] = eo; __syncthreads();
    for (int st = 256; st > 0; st >>= 1) {
        if (tid < st) red[tid] += red[tid + st];
        __syncthreads();
    }
    float zo = red[0];

    if (tid < L_) s[(b << 8) + tid] = 0.5f * (es / zs + eo / zo);
}

// ---------------- XSp[b][row][ch] bf16: row=t+1; XSp = s[b,t]*wf3[b,t,:], zero-padded
__global__ void build_xsp_kernel(const float* __restrict__ wf, const float* __restrict__ s,
                                 unsigned short* __restrict__ XSp) {
    const int CH8 = KP_ / 8;   // 152 chunks of 8
    int idx = blockIdx.x * blockDim.x + threadIdx.x;
    const int total = B_ * LROWS_ * CH8;
    if (idx >= total) return;
    int chunk = idx % CH8;
    int rb = idx / CH8;
    int row = rb % LROWS_;
    int b = rb / LROWS_;

    u16x8 out = {0,0,0,0,0,0,0,0};
    int t = row - 1;
    int ch0 = chunk * 8;
    if ((unsigned)t < (unsigned)L_ && ch0 < D3_) {
        int j = ch0 / D_;
        int d0 = ch0 - j * D_;
        int u = t + j - 1;
        if ((unsigned)u < (unsigned)L_) {
            float sc = s[(b << 8) + t];
            const float* w = wf + ((size_t)((b << 8) + u)) * D_ + d0;
#pragma unroll
            for (int q = 0; q < 8; ++q) out[q] = f2bf(sc * w[q]);
        }
    }
    *(u16x8*)&XSp[((size_t)(b * LROWS_ + row)) * KP_ + ch0] = out;
}

// ============ 256x256 role-split MFMA GEMM (r7 structure, verified 0-conflict) ============
// MODE 0: conv  — A from XSp (tap addressing), epilogue tanh(+bias) -> bf16 sent
// MODE 1: P     — A = sent, epilogue f32 -> P
// 8 waves = 2M x 4N; per-wave out 128x64. BK=64. LDS 128KB:
//   A[2 dbuf][2 Mhalf][128 rows][8 slots x 16B], B[2 dbuf][2 Nhalf][128 cols][8 slots].
// Each wave stages ONLY its own planes; slot p at row r holds global slot p^(r&7);
// reads use ((lane>>4)+kh*4)^(row&7). ONE __syncthreads per K-tile.
template<int MODE>
__global__ __launch_bounds__(512, 2) void gemm8_kernel(
    const unsigned short* __restrict__ Aglob, const unsigned short* __restrict__ Bglob,
    const float* __restrict__ conv_b, unsigned short* __restrict__ outb,
    float* __restrict__ outf) {
    extern __shared__ unsigned short lds[];
    const int tid = threadIdx.x;
    const int lane = tid & 63;
    const int wave = tid >> 6;     // 0..7
    const int wr = wave >> 2;      // 0..1  (M half)
    const int wc = wave & 3;       // 0..3  (N quarter)
    const int bx = blockIdx.x;
    const int blockN = blockIdx.y * 256;
    const int l15 = lane & 15;
    const int NT = (MODE == 0) ? (K3_ / 64) : (C_ / 64);
    const size_t Astr = (MODE == 0) ? (size_t)KP_ : (size_t)C_;
    const size_t Bstr = (MODE == 0) ? (size_t)K3_ : (size_t)C_;

    const int arole = wc;
    const int bhalf = wc >> 1;
    const int brole = wr * 2 + (wc & 1);

    const int acol0 = (((lane >> 4) + 0) ^ (l15 & 7)) * 8;
    const int acol1 = (((lane >> 4) + 4) ^ (l15 & 7)) * 8;
    const int bro = (wc & 1) * 64;

    auto stageA = [&](int kt, int buf) {
        const unsigned short* gb;
        if constexpr (MODE == 0) {
            int tap = kt / KP_, ch0 = kt - tap * KP_;
            gb = Aglob + ((size_t)(bx * LROWS_ + wr * 128 + tap)) * KP_ + ch0;
        } else {
            gb = Aglob + ((size_t)(bx * 256 + wr * 128)) * C_ + kt;
        }
        unsigned short* pb = &lds[(buf * 2 + wr) * 8192];
#pragma unroll
        for (int i = 0; i < 4; ++i) {
            int sl = arole * 256 + i * 64 + lane;
            int row = sl >> 3, p = sl & 7;
            int colg = p ^ (row & 7);
            gld16(gb + (size_t)row * Astr + colg * 8, (char*)pb + sl * 16);
        }
    };
    auto stageB = [&](int kt, int buf) {
        const unsigned short* gb = Bglob + ((size_t)(blockN + bhalf * 128)) * Bstr + kt;
        unsigned short* pb = &lds[32768 + (buf * 2 + bhalf) * 8192];
#pragma unroll
        for (int i = 0; i < 4; ++i) {
            int sl = brole * 256 + i * 64 + lane;
            int row = sl >> 3, p = sl & 7;
            int colg = p ^ (row & 7);
            gld16(gb + (size_t)row * Bstr + colg * 8, (char*)pb + sl * 16);
        }
    };

    f32x4 acc[8][4] = {};

    stageA(0, 0);
    stageB(0, 0);
    __syncthreads();

    int cur = 0;
    for (int kt = 0; kt < NT * 64; kt += 64, cur ^= 1) {
        int ktn = kt + 64;
        if (ktn >= NT * 64) ktn = 0;
        const unsigned short* Ap = &lds[(cur * 2 + wr) * 8192];
        const unsigned short* Bp = &lds[32768 + (cur * 2 + bhalf) * 8192];

        bf16x8 a[8], b0, b1;

#pragma unroll
        for (int mi = 0; mi < 8; ++mi) a[mi] = *(const bf16x8*)&Ap[(mi * 16 + l15) * 64 + acol0];
        b0 = *(const bf16x8*)&Bp[(bro + 0 * 16 + l15) * 64 + acol0];
        b1 = *(const bf16x8*)&Bp[(bro + 1 * 16 + l15) * 64 + acol0];
        stageA(ktn, cur ^ 1);
        __builtin_amdgcn_s_setprio(1);
#pragma unroll
        for (int mi = 0; mi < 8; ++mi) {
            acc[mi][0] = __builtin_amdgcn_mfma_f32_16x16x32_bf16(a[mi], b0, acc[mi][0], 0, 0, 0);
            acc[mi][1] = __builtin_amdgcn_mfma_f32_16x16x32_bf16(a[mi], b1, acc[mi][1], 0, 0, 0);
        }
        __builtin_amdgcn_s_setprio(0);

        b0 = *(const bf16x8*)&Bp[(bro + 2 * 16 + l15) * 64 + acol0];
        b1 = *(const bf16x8*)&Bp[(bro + 3 * 16 + l15) * 64 + acol0];
        stageB(ktn, cur ^ 1);
        __builtin_amdgcn_s_setprio(1);
#pragma unroll
        for (int mi = 0; mi < 8; ++mi) {
            acc[mi][2] = __builtin_amdgcn_mfma_f32_16x16x32_bf16(a[mi], b0, acc[mi][2], 0, 0, 0);
            acc[mi][3] = __builtin_amdgcn_mfma_f32_16x16x32_bf16(a[mi], b1, acc[mi][3], 0, 0, 0);
        }
        __builtin_amdgcn_s_setprio(0);

#pragma unroll
        for (int mi = 0; mi < 8; ++mi) a[mi] = *(const bf16x8*)&Ap[(mi * 16 + l15) * 64 + acol1];
        b0 = *(const bf16x8*)&Bp[(bro + 0 * 16 + l15) * 64 + acol1];
        b1 = *(const bf16x8*)&Bp[(bro + 1 * 16 + l15) * 64 + acol1];
        __builtin_amdgcn_s_setprio(1);
#pragma unroll
        for (int mi = 0; mi < 8; ++mi) {
            acc[mi][0] = __builtin_amdgcn_mfma_f32_16x16x32_bf16(a[mi], b0, acc[mi][0], 0, 0, 0);
            acc[mi][1] = __builtin_amdgcn_mfma_f32_16x16x32_bf16(a[mi], b1, acc[mi][1], 0, 0, 0);
        }
        __builtin_amdgcn_s_setprio(0);

        b0 = *(const bf16x8*)&Bp[(bro + 2 * 16 + l15) * 64 + acol1];
        b1 = *(const bf16x8*)&Bp[(bro + 3 * 16 + l15) * 64 + acol1];
        __builtin_amdgcn_s_setprio(1);
#pragma unroll
        for (int mi = 0; mi < 8; ++mi) {
            acc[mi][2] = __builtin_amdgcn_mfma_f32_16x16x32_bf16(a[mi], b0, acc[mi][2], 0, 0, 0);
            acc[mi][3] = __builtin_amdgcn_mfma_f32_16x16x32_bf16(a[mi], b1, acc[mi][3], 0, 0, 0);
        }
        __builtin_amdgcn_s_setprio(0);

        __syncthreads();
    }

    const int r4 = ((lane >> 4) << 2);
#pragma unroll
    for (int mi = 0; mi < 8; ++mi) {
#pragma unroll
        for (int nj = 0; nj < 4; ++nj) {
            const int col = blockN + wc * 64 + nj * 16 + l15;
            const int row0 = bx * 256 + wr * 128 + mi * 16 + r4;
            if constexpr (MODE == 0) {
                float bias = conv_b[col];
#pragma unroll
                for (int r = 0; r < 4; ++r)
                    outb[(size_t)(row0 + r) * C_ + col] = f2bf(tanhf(acc[mi][nj][r] + bias));
            } else {
#pragma unroll
                for (int r = 0; r < 4; ++r)
                    outf[(size_t)(row0 + r) * C_ + col] = acc[mi][nj][r];
            }
        }
    }
}

// ---------------- column softmax over L + weighted max -> wo[b,c]
__global__ __launch_bounds__(256) void softmax_wo_kernel(
    const float* __restrict__ P, const unsigned short* __restrict__ sent,
    float* __restrict__ wo) {
    const int b = blockIdx.x;
    const int c = blockIdx.y * 256 + threadIdx.x;
    const float* Pb = P + ((size_t)(b << 8)) * C_ + c;
    const unsigned short* Sb = sent + ((size_t)(b << 8)) * C_ + c;
    float m = -INFINITY;
    for (int l = 0; l < L_; ++l) m = fmaxf(m, Pb[(size_t)l * C_]);
    float z = 0.f, wmax = -INFINITY;
    for (int l = 0; l < L_; ++l) {
        float e = expf(Pb[(size_t)l * C_] - m);
        z += e;
        wmax = fmaxf(wmax, bf2f(Sb[(size_t)l * C_]) * e);
    }
    wo[b * C_ + c] = wmax / z;
}

// ---------------- normalize + distances
__global__ __launch_bounds__(256) void final_kernel(
    const float* __restrict__ wo, const float* __restrict__ re, float* __restrict__ out) {
    const int b = blockIdx.x, tid = threadIdx.x;
    __shared__ float won[C_];
    __shared__ float red[256];
    float p = 0.f;
    for (int c = tid; c < C_; c += 256) {
        float v = wo[b * C_ + c];
        p += v * v;
    }
    red[tid] = p; __syncthreads();
    for (int st = 128; st > 0; st >>= 1) {
        if (tid < st) red[tid] += red[tid + st];
        __syncthreads();
    }
    float inv = 1.f / fmaxf(sqrtf(red[0]), 1e-12f);
    for (int c = tid; c < C_; c += 256) won[c] = wo[b * C_ + c] * inv;
    __syncthreads();
    const int wv = tid >> 6, lane = tid & 63;
    for (int r = wv; r < R_; r += 4) {
        float acc2 = 0.f;
        for (int c = lane; c < C_; c += 64) {
            float dlt = won[c] - re[r * C_ + c];
            acc2 += dlt * dlt;
        }
        for (int off = 32; off > 0; off >>= 1) acc2 += __shfl_down(acc2, off);
        if (lane == 0) out[b * R_ + r] = sqrtf(acc2);
    }
}

// ---------------- launch ----------------
extern "C" void kernel_launch(void* const* d_in, const int* in_sizes, int n_in,
                              void* d_out, int out_size, void* d_ws, size_t ws_size,
                              hipStream_t stream) {
    const int* context     = (const int*)d_in[0];
    const int* subject_idx = (const int*)d_in[1];
    const int* object_idx  = (const int*)d_in[2];
    const int* subject_dis = (const int*)d_in[3];
    const int* object_dis  = (const int*)d_in[4];
    const float* embed_table = (const float*)d_in[5];
    const float* pos_table   = (const float*)d_in[6];
    const float* conv_w      = (const float*)d_in[7];
    const float* conv_b      = (const float*)d_in[8];
    const float* rlw         = (const float*)d_in[9];
    const float* re          = (const float*)d_in[10];
    float* out = (float*)d_out;

    char* ws = (char*)d_ws;
    size_t off = 0;
    auto alloc = [&](size_t bytes) {
        void* p = ws + off;
        off = (off + bytes + 255) & ~(size_t)255;
        return p;
    };
    float* wf            = (float*)alloc((size_t)M_ * D_ * 4);            // 52.4 MB
    float* s             = (float*)alloc((size_t)M_ * 4);                 // 0.13 MB
    unsigned short* XSp  = (unsigned short*)alloc((size_t)B_ * LROWS_ * KP_ * 2); // 80.3 MB
    unsigned short* WpT  = (unsigned short*)alloc((size_t)C_ * K3_ * 2);  // 3.7 MB
    unsigned short* MmatT= (unsigned short*)alloc((size_t)C_ * C_ * 2);   // 0.5 MB
    unsigned short* sent = (unsigned short*)alloc((size_t)M_ * C_ * 2);   // 33.6 MB
    float* wo            = (float*)alloc((size_t)B_ * C_ * 4);            // 0.26 MB
    // alias: XSp dead after conv gemm; P (67 MB) fits in its 80.3 MB
    float* P = (float*)XSp;

    (void)hipFuncSetAttribute((const void*)gemm8_kernel<0>,
                              hipFuncAttributeMaxDynamicSharedMemorySize, 131072);
    (void)hipFuncSetAttribute((const void*)gemm8_kernel<1>,
                              hipFuncAttributeMaxDynamicSharedMemorySize, 131072);

    prep_wpT_kernel<<<(C_ * K3_ + 255) / 256, 256, 0, stream>>>(conv_w, WpT);
    prep_mT_kernel<<<(C_ * C_ + 255) / 256, 256, 0, stream>>>(rlw, re, MmatT);
    build_wf_kernel<<<4096, 256, 0, stream>>>(context, subject_dis, object_dis,
                                              embed_table, pos_table, wf);
    // fused attention-scale (span sums + dots + softmax) -> s
    attn_fused_kernel<<<B_, 512, 0, stream>>>(wf, subject_idx, object_idx, s);
    // conv input
    build_xsp_kernel<<<(B_ * LROWS_ * (KP_ / 8) + 255) / 256, 256, 0, stream>>>(wf, s, XSp);
    // conv -> sent (256^2 role-split MFMA, r7-proven)
    gemm8_kernel<0><<<dim3(M_ / 256, C_ / 256), 512, 131072, stream>>>(
        XSp, WpT, conv_b, sent, nullptr);
    // P = sent @ Mmat
    gemm8_kernel<1><<<dim3(M_ / 256, C_ / 256), 512, 131072, stream>>>(
        sent, MmatT, nullptr, nullptr, P);
    // softmax over L + weighted max
    softmax_wo_kernel<<<dim3(B_, 2), 256, 0, stream>>>(P, sent, wo);
    // normalize + distances
    final_kernel<<<B_, 256, 0, stream>>>(wo, re, out);
}

// Round 12
// 345.579 us; speedup vs baseline: 1.1328x; 1.1328x over previous
//
#include <hip/hip_runtime.h>
#include <hip/hip_bf16.h>
#include <math.h>

// Problem constants
#define B_  128
#define L_  256
#define E_  300
#define PF_ 50
#define D_  400      // E + 2*PF
#define D3_ 1200     // 3*D
#define C_  512
#define KW_ 3
#define R_  53
#define M_  (B_*L_)  // 32768
#define KP_ 1216     // padded per-tap K (1200 -> 1216, divisible by 64)
#define K3_ (3*KP_)  // 3648 total GEMM K
#define LROWS_ 258   // L + 2 padded rows per batch in XSp

typedef __attribute__((ext_vector_type(8))) short bf16x8;
typedef __attribute__((ext_vector_type(8))) unsigned short u16x8;
typedef __attribute__((ext_vector_type(4))) float f32x4;

__device__ __forceinline__ unsigned short f2bf(float f) {
    union { float f; unsigned u; } x; x.f = f;
    unsigned r = x.u + 0x7FFF + ((x.u >> 16) & 1);
    return (unsigned short)(r >> 16);
}
__device__ __forceinline__ float bf2f(unsigned short u) {
    union { unsigned u; float f; } x; x.u = ((unsigned)u) << 16;
    return x.f;
}

__device__ __forceinline__ void gld16(const void* g, void* l) {
    __builtin_amdgcn_global_load_lds(
        (const __attribute__((address_space(1))) void*)g,
        (__attribute__((address_space(3))) void*)l, 16, 0, 0);
}

// ---------------- prep: WpT[c][q] = conv_w[c, ch, k], q = k*1216+ch, zero-pad ch>=1200
__global__ void prep_wpT_kernel(const float* __restrict__ conv_w, unsigned short* __restrict__ WpT) {
    int idx = blockIdx.x * blockDim.x + threadIdx.x;
    if (idx >= C_ * K3_) return;
    int c = idx / K3_, q = idx % K3_;
    int k = q / KP_, ch = q % KP_;
    WpT[idx] = (ch < D3_) ? f2bf(conv_w[c * (D3_ * KW_) + ch * KW_ + k]) : (unsigned short)0;
}

// ---------------- prep: MmatT[n][k] = sum_r rlw[r,k]*re[r,n]  (bf16)
__global__ void prep_mT_kernel(const float* __restrict__ rlw, const float* __restrict__ re,
                               unsigned short* __restrict__ MmatT) {
    int idx = blockIdx.x * blockDim.x + threadIdx.x;
    if (idx >= C_ * C_) return;
    int n = idx / C_, k = idx % C_;
    float acc = 0.f;
    for (int r = 0; r < R_; ++r)
        acc += rlw[r * C_ + k] * re[r * C_ + n];
    MmatT[idx] = f2bf(acc);
}

// ---------------- wf[b,t,d] f32
__global__ void build_wf_kernel(const int* __restrict__ ctx, const int* __restrict__ sdis,
                                const int* __restrict__ odis, const float* __restrict__ emb,
                                const float* __restrict__ pos, float* __restrict__ wf) {
    const int total = M_ * D_;
    for (int idx = blockIdx.x * blockDim.x + threadIdx.x; idx < total;
         idx += gridDim.x * blockDim.x) {
        int d = idx % D_;
        int bt = idx / D_;
        float v;
        if (d < E_)            v = emb[(long)ctx[bt] * E_ + d];
        else if (d < E_ + PF_) v = pos[sdis[bt] * PF_ + (d - E_)];
        else                   v = pos[odis[bt] * PF_ + (d - E_ - PF_)];
        wf[idx] = v;
    }
}

// ---------------- direct span sums -> SS/OS[b][j][d] (replaces prefix+span_mean)
// Block (b, e): base = sum rows [s0,s1] (j=1); j=0/j=2 by +-1-row edge correction,
// algebraically identical to the clamped-prefix formula (verified at all edges).
__global__ __launch_bounds__(512) void span_sum_kernel(
    const float* __restrict__ wf, const int* __restrict__ sidx, const int* __restrict__ oidx,
    float* __restrict__ SS, float* __restrict__ OS) {
    const int b = blockIdx.x, e = blockIdx.y;
    const int* idx = e ? oidx : sidx;
    float* out = e ? OS : SS;
    const int s0 = idx[b * 2], s1 = idx[b * 2 + 1];
    const float inv = 1.f / (float)(s1 - s0 + 1);
    const int d = threadIdx.x;
    if (d >= D_) return;

    const float* base_p = wf + (size_t)(b << 8) * D_ + d;
    float base = 0.f;
    for (int t = s0; t <= s1; ++t) base += base_p[(size_t)t * D_];

    float w_s0 = base_p[(size_t)s0 * D_];
    float w_s1 = base_p[(size_t)s1 * D_];
    float j0 = base - w_s1 + ((s0 > 0) ? base_p[(size_t)(s0 - 1) * D_] : 0.f);
    float j2 = base - w_s0 + ((s1 < L_ - 1) ? base_p[(size_t)(s1 + 1) * D_] : 0.f);

    out[((size_t)(b * 3 + 0)) * D_ + d] = j0 * inv;
    out[((size_t)(b * 3 + 1)) * D_ + d] = base * inv;
    out[((size_t)(b * 3 + 2)) * D_ + d] = j2 * inv;
}

// ---------------- dots: one wave per (b,t)
__global__ __launch_bounds__(256) void dots_kernel(
    const float* __restrict__ wf, const float* __restrict__ SS, const float* __restrict__ OS,
    float* __restrict__ dsb, float* __restrict__ ddb) {
    const int wave = threadIdx.x >> 6, lane = threadIdx.x & 63;
    const int g = blockIdx.x * 4 + wave;   // (b<<8)+t
    const int b = g >> 8, t = g & 255;
    float ds = 0.f, dd = 0.f;
#pragma unroll
    for (int j = 0; j < 3; ++j) {
        int u = t + j - 1;
        if ((unsigned)u < (unsigned)L_) {
            const float4* w  = (const float4*)(wf + ((size_t)((b << 8) + u)) * D_);
            const float4* ss = (const float4*)(SS + ((size_t)(b * 3 + j)) * D_);
            const float4* oo = (const float4*)(OS + ((size_t)(b * 3 + j)) * D_);
            for (int q = lane; q < D_ / 4; q += 64) {
                float4 wv = w[q], sv = ss[q], ov = oo[q];
                ds += wv.x * sv.x + wv.y * sv.y + wv.z * sv.z + wv.w * sv.w;
                dd += wv.x * ov.x + wv.y * ov.y + wv.z * ov.z + wv.w * ov.w;
            }
        }
    }
#pragma unroll
    for (int off = 32; off > 0; off >>= 1) {
        ds += __shfl_down(ds, off);
        dd += __shfl_down(dd, off);
    }
    if (lane == 0) { dsb[g] = ds; ddb[g] = dd; }
}

// ---------------- softmax over t (per b) -> s[b,t]
__global__ __launch_bounds__(256) void softmax_s_kernel(
    const float* __restrict__ dsb, const float* __restrict__ ddb, float* __restrict__ s) {
    const int b = blockIdx.x, tid = threadIdx.x;
    __shared__ float red[256];
    float ds = dsb[(b << 8) + tid];
    float dd = ddb[(b << 8) + tid];

    red[tid] = ds; __syncthreads();
    for (int st = 128; st > 0; st >>= 1) {
        if (tid < st) red[tid] = fmaxf(red[tid], red[tid + st]);
        __syncthreads();
    }
    float ms = red[0]; __syncthreads();
    float es = expf(ds - ms);
    red[tid] = es; __syncthreads();
    for (int st = 128; st > 0; st >>= 1) {
        if (tid < st) red[tid] += red[tid + st];
        __syncthreads();
    }
    float zs = red[0]; __syncthreads();

    red[tid] = dd; __syncthreads();
    for (int st = 128; st > 0; st >>= 1) {
        if (tid < st) red[tid] = fmaxf(red[tid], red[tid + st]);
        __syncthreads();
    }
    float mo = red[0]; __syncthreads();
    float eo = expf(dd - mo);
    red[tid] = eo; __syncthreads();
    for (int st = 128; st > 0; st >>= 1) {
        if (tid < st) red[tid] += red[tid + st];
        __syncthreads();
    }
    float zo = red[0];

    s[(b << 8) + tid] = 0.5f * (es / zs + eo / zo);
}

// ---------------- XSp[b][row][ch] bf16: row=t+1; XSp = s[b,t]*wf3[b,t,:], zero-padded
__global__ void build_xsp_kernel(const float* __restrict__ wf, const float* __restrict__ s,
                                 unsigned short* __restrict__ XSp) {
    const int CH8 = KP_ / 8;   // 152 chunks of 8
    int idx = blockIdx.x * blockDim.x + threadIdx.x;
    const int total = B_ * LROWS_ * CH8;
    if (idx >= total) return;
    int chunk = idx % CH8;
    int rb = idx / CH8;
    int row = rb % LROWS_;
    int b = rb / LROWS_;

    u16x8 out = {0,0,0,0,0,0,0,0};
    int t = row - 1;
    int ch0 = chunk * 8;
    if ((unsigned)t < (unsigned)L_ && ch0 < D3_) {
        int j = ch0 / D_;
        int d0 = ch0 - j * D_;
        int u = t + j - 1;
        if ((unsigned)u < (unsigned)L_) {
            float sc = s[(b << 8) + t];
            const float* w = wf + ((size_t)((b << 8) + u)) * D_ + d0;
#pragma unroll
            for (int q = 0; q < 8; ++q) out[q] = f2bf(sc * w[q]);
        }
    }
    *(u16x8*)&XSp[((size_t)(b * LROWS_ + row)) * KP_ + ch0] = out;
}

// ============ 256x256 role-split MFMA GEMM (r7 structure, verified 0-conflict) ============
// MODE 0: conv  — A from XSp (tap addressing), epilogue tanh(+bias) -> bf16 sent
// MODE 1: P     — A = sent, epilogue f32 -> P
// 8 waves = 2M x 4N; per-wave out 128x64. BK=64. LDS 128KB:
//   A[2 dbuf][2 Mhalf][128 rows][8 slots x 16B], B[2 dbuf][2 Nhalf][128 cols][8 slots].
// Each wave stages ONLY its own planes; slot p at row r holds global slot p^(r&7);
// reads use ((lane>>4)+kh*4)^(row&7). ONE __syncthreads per K-tile.
template<int MODE>
__global__ __launch_bounds__(512, 2) void gemm8_kernel(
    const unsigned short* __restrict__ Aglob, const unsigned short* __restrict__ Bglob,
    const float* __restrict__ conv_b, unsigned short* __restrict__ outb,
    float* __restrict__ outf) {
    extern __shared__ unsigned short lds[];
    const int tid = threadIdx.x;
    const int lane = tid & 63;
    const int wave = tid >> 6;     // 0..7
    const int wr = wave >> 2;      // 0..1  (M half)
    const int wc = wave & 3;       // 0..3  (N quarter)
    const int bx = blockIdx.x;
    const int blockN = blockIdx.y * 256;
    const int l15 = lane & 15;
    const int NT = (MODE == 0) ? (K3_ / 64) : (C_ / 64);
    const size_t Astr = (MODE == 0) ? (size_t)KP_ : (size_t)C_;
    const size_t Bstr = (MODE == 0) ? (size_t)K3_ : (size_t)C_;

    const int arole = wc;
    const int bhalf = wc >> 1;
    const int brole = wr * 2 + (wc & 1);

    const int acol0 = (((lane >> 4) + 0) ^ (l15 & 7)) * 8;
    const int acol1 = (((lane >> 4) + 4) ^ (l15 & 7)) * 8;
    const int bro = (wc & 1) * 64;

    auto stageA = [&](int kt, int buf) {
        const unsigned short* gb;
        if constexpr (MODE == 0) {
            int tap = kt / KP_, ch0 = kt - tap * KP_;
            gb = Aglob + ((size_t)(bx * LROWS_ + wr * 128 + tap)) * KP_ + ch0;
        } else {
            gb = Aglob + ((size_t)(bx * 256 + wr * 128)) * C_ + kt;
        }
        unsigned short* pb = &lds[(buf * 2 + wr) * 8192];
#pragma unroll
        for (int i = 0; i < 4; ++i) {
            int sl = arole * 256 + i * 64 + lane;
            int row = sl >> 3, p = sl & 7;
            int colg = p ^ (row & 7);
            gld16(gb + (size_t)row * Astr + colg * 8, (char*)pb + sl * 16);
        }
    };
    auto stageB = [&](int kt, int buf) {
        const unsigned short* gb = Bglob + ((size_t)(blockN + bhalf * 128)) * Bstr + kt;
        unsigned short* pb = &lds[32768 + (buf * 2 + bhalf) * 8192];
#pragma unroll
        for (int i = 0; i < 4; ++i) {
            int sl = brole * 256 + i * 64 + lane;
            int row = sl >> 3, p = sl & 7;
            int colg = p ^ (row & 7);
            gld16(gb + (size_t)row * Bstr + colg * 8, (char*)pb + sl * 16);
        }
    };

    f32x4 acc[8][4] = {};

    stageA(0, 0);
    stageB(0, 0);
    __syncthreads();

    int cur = 0;
    for (int kt = 0; kt < NT * 64; kt += 64, cur ^= 1) {
        int ktn = kt + 64;
        if (ktn >= NT * 64) ktn = 0;
        const unsigned short* Ap = &lds[(cur * 2 + wr) * 8192];
        const unsigned short* Bp = &lds[32768 + (cur * 2 + bhalf) * 8192];

        bf16x8 a[8], b0, b1;

#pragma unroll
        for (int mi = 0; mi < 8; ++mi) a[mi] = *(const bf16x8*)&Ap[(mi * 16 + l15) * 64 + acol0];
        b0 = *(const bf16x8*)&Bp[(bro + 0 * 16 + l15) * 64 + acol0];
        b1 = *(const bf16x8*)&Bp[(bro + 1 * 16 + l15) * 64 + acol0];
        stageA(ktn, cur ^ 1);
        __builtin_amdgcn_s_setprio(1);
#pragma unroll
        for (int mi = 0; mi < 8; ++mi) {
            acc[mi][0] = __builtin_amdgcn_mfma_f32_16x16x32_bf16(a[mi], b0, acc[mi][0], 0, 0, 0);
            acc[mi][1] = __builtin_amdgcn_mfma_f32_16x16x32_bf16(a[mi], b1, acc[mi][1], 0, 0, 0);
        }
        __builtin_amdgcn_s_setprio(0);

        b0 = *(const bf16x8*)&Bp[(bro + 2 * 16 + l15) * 64 + acol0];
        b1 = *(const bf16x8*)&Bp[(bro + 3 * 16 + l15) * 64 + acol0];
        stageB(ktn, cur ^ 1);
        __builtin_amdgcn_s_setprio(1);
#pragma unroll
        for (int mi = 0; mi < 8; ++mi) {
            acc[mi][2] = __builtin_amdgcn_mfma_f32_16x16x32_bf16(a[mi], b0, acc[mi][2], 0, 0, 0);
            acc[mi][3] = __builtin_amdgcn_mfma_f32_16x16x32_bf16(a[mi], b1, acc[mi][3], 0, 0, 0);
        }
        __builtin_amdgcn_s_setprio(0);

#pragma unroll
        for (int mi = 0; mi < 8; ++mi) a[mi] = *(const bf16x8*)&Ap[(mi * 16 + l15) * 64 + acol1];
        b0 = *(const bf16x8*)&Bp[(bro + 0 * 16 + l15) * 64 + acol1];
        b1 = *(const bf16x8*)&Bp[(bro + 1 * 16 + l15) * 64 + acol1];
        __builtin_amdgcn_s_setprio(1);
#pragma unroll
        for (int mi = 0; mi < 8; ++mi) {
            acc[mi][0] = __builtin_amdgcn_mfma_f32_16x16x32_bf16(a[mi], b0, acc[mi][0], 0, 0, 0);
            acc[mi][1] = __builtin_amdgcn_mfma_f32_16x16x32_bf16(a[mi], b1, acc[mi][1], 0, 0, 0);
        }
        __builtin_amdgcn_s_setprio(0);

        b0 = *(const bf16x8*)&Bp[(bro + 2 * 16 + l15) * 64 + acol1];
        b1 = *(const bf16x8*)&Bp[(bro + 3 * 16 + l15) * 64 + acol1];
        __builtin_amdgcn_s_setprio(1);
#pragma unroll
        for (int mi = 0; mi < 8; ++mi) {
            acc[mi][2] = __builtin_amdgcn_mfma_f32_16x16x32_bf16(a[mi], b0, acc[mi][2], 0, 0, 0);
            acc[mi][3] = __builtin_amdgcn_mfma_f32_16x16x32_bf16(a[mi], b1, acc[mi][3], 0, 0, 0);
        }
        __builtin_amdgcn_s_setprio(0);

        __syncthreads();
    }

    const int r4 = ((lane >> 4) << 2);
#pragma unroll
    for (int mi = 0; mi < 8; ++mi) {
#pragma unroll
        for (int nj = 0; nj < 4; ++nj) {
            const int col = blockN + wc * 64 + nj * 16 + l15;
            const int row0 = bx * 256 + wr * 128 + mi * 16 + r4;
            if constexpr (MODE == 0) {
                float bias = conv_b[col];
#pragma unroll
                for (int r = 0; r < 4; ++r)
                    outb[(size_t)(row0 + r) * C_ + col] = f2bf(tanhf(acc[mi][nj][r] + bias));
            } else {
#pragma unroll
                for (int r = 0; r < 4; ++r)
                    outf[(size_t)(row0 + r) * C_ + col] = acc[mi][nj][r];
            }
        }
    }
}

// ---------------- column softmax over L + weighted max -> wo[b,c]
__global__ __launch_bounds__(256) void softmax_wo_kernel(
    const float* __restrict__ P, const unsigned short* __restrict__ sent,
    float* __restrict__ wo) {
    const int b = blockIdx.x;
    const int c = blockIdx.y * 256 + threadIdx.x;
    const float* Pb = P + ((size_t)(b << 8)) * C_ + c;
    const unsigned short* Sb = sent + ((size_t)(b << 8)) * C_ + c;
    float m = -INFINITY;
    for (int l = 0; l < L_; ++l) m = fmaxf(m, Pb[(size_t)l * C_]);
    float z = 0.f, wmax = -INFINITY;
    for (int l = 0; l < L_; ++l) {
        float e = expf(Pb[(size_t)l * C_] - m);
        z += e;
        wmax = fmaxf(wmax, bf2f(Sb[(size_t)l * C_]) * e);
    }
    wo[b * C_ + c] = wmax / z;
}

// ---------------- normalize + distances
__global__ __launch_bounds__(256) void final_kernel(
    const float* __restrict__ wo, const float* __restrict__ re, float* __restrict__ out) {
    const int b = blockIdx.x, tid = threadIdx.x;
    __shared__ float won[C_];
    __shared__ float red[256];
    float p = 0.f;
    for (int c = tid; c < C_; c += 256) {
        float v = wo[b * C_ + c];
        p += v * v;
    }
    red[tid] = p; __syncthreads();
    for (int st = 128; st > 0; st >>= 1) {
        if (tid < st) red[tid] += red[tid + st];
        __syncthreads();
    }
    float inv = 1.f / fmaxf(sqrtf(red[0]), 1e-12f);
    for (int c = tid; c < C_; c += 256) won[c] = wo[b * C_ + c] * inv;
    __syncthreads();
    const int wv = tid >> 6, lane = tid & 63;
    for (int r = wv; r < R_; r += 4) {
        float acc2 = 0.f;
        for (int c = lane; c < C_; c += 64) {
            float dlt = won[c] - re[r * C_ + c];
            acc2 += dlt * dlt;
        }
        for (int off = 32; off > 0; off >>= 1) acc2 += __shfl_down(acc2, off);
        if (lane == 0) out[b * R_ + r] = sqrtf(acc2);
    }
}

// ---------------- launch ----------------
extern "C" void kernel_launch(void* const* d_in, const int* in_sizes, int n_in,
                              void* d_out, int out_size, void* d_ws, size_t ws_size,
                              hipStream_t stream) {
    const int* context     = (const int*)d_in[0];
    const int* subject_idx = (const int*)d_in[1];
    const int* object_idx  = (const int*)d_in[2];
    const int* subject_dis = (const int*)d_in[3];
    const int* object_dis  = (const int*)d_in[4];
    const float* embed_table = (const float*)d_in[5];
    const float* pos_table   = (const float*)d_in[6];
    const float* conv_w      = (const float*)d_in[7];
    const float* conv_b      = (const float*)d_in[8];
    const float* rlw         = (const float*)d_in[9];
    const float* re          = (const float*)d_in[10];
    float* out = (float*)d_out;

    char* ws = (char*)d_ws;
    size_t off = 0;
    auto alloc = [&](size_t bytes) {
        void* p = ws + off;
        off = (off + bytes + 255) & ~(size_t)255;
        return p;
    };
    float* wf            = (float*)alloc((size_t)M_ * D_ * 4);            // 52.4 MB
    float* s             = (float*)alloc((size_t)M_ * 4);                 // 0.13 MB
    unsigned short* XSp  = (unsigned short*)alloc((size_t)B_ * LROWS_ * KP_ * 2); // 80.3 MB
    unsigned short* WpT  = (unsigned short*)alloc((size_t)C_ * K3_ * 2);  // 3.7 MB
    unsigned short* MmatT= (unsigned short*)alloc((size_t)C_ * C_ * 2);   // 0.5 MB
    unsigned short* sent = (unsigned short*)alloc((size_t)M_ * C_ * 2);   // 33.6 MB
    float* wo            = (float*)alloc((size_t)B_ * C_ * 4);            // 0.26 MB
    float* SS            = (float*)alloc((size_t)B_ * 3 * D_ * 4);        // 0.61 MB
    float* OS            = (float*)alloc((size_t)B_ * 3 * D_ * 4);        // 0.61 MB
    float* dsb           = (float*)alloc((size_t)M_ * 4);                 // 0.13 MB
    float* ddb           = (float*)alloc((size_t)M_ * 4);                 // 0.13 MB
    // alias: XSp dead after conv gemm; P (67 MB) fits in its 80.3 MB
    float* P = (float*)XSp;

    (void)hipFuncSetAttribute((const void*)gemm8_kernel<0>,
                              hipFuncAttributeMaxDynamicSharedMemorySize, 131072);
    (void)hipFuncSetAttribute((const void*)gemm8_kernel<1>,
                              hipFuncAttributeMaxDynamicSharedMemorySize, 131072);

    prep_wpT_kernel<<<(C_ * K3_ + 255) / 256, 256, 0, stream>>>(conv_w, WpT);
    prep_mT_kernel<<<(C_ * C_ + 255) / 256, 256, 0, stream>>>(rlw, re, MmatT);
    build_wf_kernel<<<4096, 256, 0, stream>>>(context, subject_dis, object_dis,
                                              embed_table, pos_table, wf);
    // attention-scale phase (parallel, r7-proven structure; direct span sums)
    span_sum_kernel<<<dim3(B_, 2), 512, 0, stream>>>(wf, subject_idx, object_idx, SS, OS);
    dots_kernel<<<M_ / 4, 256, 0, stream>>>(wf, SS, OS, dsb, ddb);
    softmax_s_kernel<<<B_, 256, 0, stream>>>(dsb, ddb, s);
    // conv input
    build_xsp_kernel<<<(B_ * LROWS_ * (KP_ / 8) + 255) / 256, 256, 0, stream>>>(wf, s, XSp);
    // conv -> sent (256^2 role-split MFMA, r7-proven)
    gemm8_kernel<0><<<dim3(M_ / 256, C_ / 256), 512, 131072, stream>>>(
        XSp, WpT, conv_b, sent, nullptr);
    // P = sent @ Mmat
    gemm8_kernel<1><<<dim3(M_ / 256, C_ / 256), 512, 131072, stream>>>(
        sent, MmatT, nullptr, nullptr, P);
    // softmax over L + weighted max
    softmax_wo_kernel<<<dim3(B_, 2), 256, 0, stream>>>(P, sent, wo);
    // normalize + distances
    final_kernel<<<B_, 256, 0, stream>>>(wo, re, out);
}